// Round 10
// baseline (831.724 us; speedup 1.0000x reference)
//
#include <hip/hip_runtime.h>
#include <math.h>

#define BATCH 2
#define NCH 21
#define CPAD 24            // channels padded to 24 (48 B fp16 per pixel)
#define HH 512
#define WW 512
#define KS 5
#define RAD 2
#define NTAPS 25
#define NUM_ITERS 10

// weights-kernel tile geometry
#define TXW 32
#define TYW 8
#define HXW (TXW + 2*RAD)   // 36
#define HYW (TYW + 2*RAD)   // 12
#define HPXW (HXW * HYW)    // 432

// fused-pair kernel geometry: 32x32 inner tile, 512 threads, vertical px pair per thread
#define TW 32
#define TH 32
#define NTHR 512
#define SX 40               // staged tile (4-px halo for 2 iters)
#define SY 40
#define SPX (SX * SY)       // 1600
#define SCHUNK (SPX * 3)    // 4800 16-byte DMA chunks
#define EX 36               // extended (iter-1 output) region
#define EY 36
#define EPX (EX * EY)       // 1296
#define RING (EPX - TW*TH)  // 272 ring pixels

typedef _Float16 f16;
typedef _Float16 half8 __attribute__((ext_vector_type(8)));
typedef _Float16 half2v __attribute__((ext_vector_type(2)));

__device__ __forceinline__ int refl(int i, int n) {
    if (i < 0) i = -i;
    if (i >= n) i = 2*n - 2 - i;
    return i;
}

// weight-element selector (t is a compile-time constant after unrolling)
#define WSEL(h0, h1, h2, hl, t) \
    ((t) < 8 ? (h0)[(t)] : (t) < 16 ? (h1)[(t) - 8] : (t) < 24 ? (h2)[(t) - 16] : (hl))

// ---------------- Kernel A: combined normalized weights ----------------
// layout: wcA[px][24 halfs] (taps 0..23 interleaved) + wcB16[px] (tap 24)
__global__ __launch_bounds__(256) void weights_kernel(const float* __restrict__ image,
                                                      const float* __restrict__ edges,
                                                      f16* __restrict__ wcA,
                                                      f16* __restrict__ wcB16) {
    __shared__ float sr_[HYW][HXW];
    __shared__ float sg_[HYW][HXW];
    __shared__ float sb_[HYW][HXW];
    __shared__ float se_[HYW][HXW];

    const int tx = threadIdx.x;
    const int ty = threadIdx.y;
    const int tid = ty * TXW + tx;
    const int x0 = blockIdx.x * TXW;
    const int y0 = blockIdx.y * TYW;
    const int b = blockIdx.z;
    const int x = x0 + tx;
    const int y = y0 + ty;
    const size_t plane = (size_t)HH * WW;
    const float* img = image + (size_t)b * 3 * plane;
    const float* edg = edges + (size_t)b * plane;

    for (int i = tid; i < HPXW; i += TXW * TYW) {
        int ly = i / HXW, lx = i - ly * HXW;
        int gy = refl(y0 + ly - RAD, HH);
        int gx = refl(x0 + lx - RAD, WW);
        int g = gy * WW + gx;
        sr_[ly][lx] = img[g];
        sg_[ly][lx] = img[plane + g];
        sb_[ly][lx] = img[2 * plane + g];
        se_[ly][lx] = edg[g];
    }
    __syncthreads();

    float gs[3];
    gs[0] = 1.0f; gs[1] = __expf(-1.0f / 50.0f); gs[2] = __expf(-4.0f / 50.0f);
    float gb[3];
    gb[0] = 1.0f; gb[1] = __expf(-2.0f); gb[2] = __expf(-8.0f);
    float gbs = gb[0] + 2.0f * (gb[1] + gb[2]);
    gb[0] /= gbs; gb[1] /= gbs; gb[2] /= gbs;

    const float r0 = sr_[ty + RAD][tx + RAD];
    const float g0 = sg_[ty + RAD][tx + RAD];
    const float b0 = sb_[ty + RAD][tx + RAD];
    const float e0 = se_[ty + RAD][tx + RAD];

    float wr[NTAPS], we[NTAPS];
    float sr = 0.f, se = 0.f;
#pragma unroll
    for (int dy = 0; dy < KS; dy++) {
#pragma unroll
        for (int dx = 0; dx < KS; dx++) {
            float sp = gs[abs(dy - RAD)] * gs[abs(dx - RAD)];
            float d = fabsf(sr_[ty + dy][tx + dx] - r0)
                    + fabsf(sg_[ty + dy][tx + dx] - g0)
                    + fabsf(sb_[ty + dy][tx + dx] - b0);
            float w1 = sp * __expf(-2.0f * d * d);
            float de = fabsf(se_[ty + dy][tx + dx] - e0);
            float w2 = sp * __expf(-2.0f * de * de);
            wr[dy * KS + dx] = w1;
            we[dy * KS + dx] = w2;
            sr += w1;
            se += w2;
        }
    }
    float isr = 1.0f / sr, ise = 1.0f / se;
    float wt[NTAPS];
#pragma unroll
    for (int t = 0; t < NTAPS; t++) {
        int dy = t / KS, dx = t % KS;
        float g2 = gb[abs(dy - RAD)] * gb[abs(dx - RAD)];
        wt[t] = g2 + wr[t] * isr + we[t] * ise;
    }
    const size_t pixoff = (size_t)b * plane + (size_t)y * WW + x;
    half8* wo = (half8*)(wcA + pixoff * 24);
#pragma unroll
    for (int g = 0; g < 3; g++) {
        half8 v;
#pragma unroll
        for (int k = 0; k < 8; k++) v[k] = (f16)wt[g * 8 + k];
        wo[g] = v;
    }
    wcB16[pixoff] = (f16)wt[24];
}

// ---------------- Kernel B: initial softmax -> interleaved fp16 q + fp16 unary ----------------
__global__ void init_kernel(const float* __restrict__ unary,
                            f16* __restrict__ q,
                            f16* __restrict__ u16) {
    int idx = blockIdx.x * blockDim.x + threadIdx.x;
    if (idx >= BATCH * HH * WW) return;
    int p = idx % (HH * WW);
    int b = idx / (HH * WW);
    const size_t plane = (size_t)HH * WW;
    const float* u = unary + (size_t)b * NCH * plane + p;
    float l[CPAD];
    float m = -1e30f;
#pragma unroll
    for (int c = 0; c < NCH; c++) { l[c] = u[c * plane]; m = fmaxf(m, l[c]); }
    l[21] = 0.f; l[22] = 0.f; l[23] = 0.f;

    half8* uo = (half8*)(u16 + ((size_t)b * plane + p) * CPAD);
#pragma unroll
    for (int g = 0; g < 3; g++) {
        half8 v;
#pragma unroll
        for (int k = 0; k < 8; k++) v[k] = (f16)l[g * 8 + k];
        uo[g] = v;
    }

    float s = 0.f;
    float e[CPAD];
#pragma unroll
    for (int c = 0; c < NCH; c++) { e[c] = __expf(l[c] - m); s += e[c]; }
    float is = 1.0f / s;
    e[21] = 0.f; e[22] = 0.f; e[23] = 0.f;
    half8* qo = (half8*)(q + ((size_t)b * plane + p) * CPAD);
#pragma unroll
    for (int g = 0; g < 3; g++) {
        half8 v;
#pragma unroll
        for (int k = 0; k < 8; k++) v[k] = (f16)(e[g * 8 + k] * is);
        qo[g] = v;
    }
}

// packed-f16 FMA of one tap into an 11-element half2 accumulator
#define TAP_PK(acc2, v0, v1, v2, wv_)                                                           \
    {                                                                                           \
        acc2[0]  = __builtin_elementwise_fma(wv_, __builtin_shufflevector(v0, v0, 0, 1), acc2[0]);  \
        acc2[1]  = __builtin_elementwise_fma(wv_, __builtin_shufflevector(v0, v0, 2, 3), acc2[1]);  \
        acc2[2]  = __builtin_elementwise_fma(wv_, __builtin_shufflevector(v0, v0, 4, 5), acc2[2]);  \
        acc2[3]  = __builtin_elementwise_fma(wv_, __builtin_shufflevector(v0, v0, 6, 7), acc2[3]);  \
        acc2[4]  = __builtin_elementwise_fma(wv_, __builtin_shufflevector(v1, v1, 0, 1), acc2[4]);  \
        acc2[5]  = __builtin_elementwise_fma(wv_, __builtin_shufflevector(v1, v1, 2, 3), acc2[5]);  \
        acc2[6]  = __builtin_elementwise_fma(wv_, __builtin_shufflevector(v1, v1, 4, 5), acc2[6]);  \
        acc2[7]  = __builtin_elementwise_fma(wv_, __builtin_shufflevector(v1, v1, 6, 7), acc2[7]);  \
        acc2[8]  = __builtin_elementwise_fma(wv_, __builtin_shufflevector(v2, v2, 0, 1), acc2[8]);  \
        acc2[9]  = __builtin_elementwise_fma(wv_, __builtin_shufflevector(v2, v2, 2, 3), acc2[9]);  \
        acc2[10] = __builtin_elementwise_fma(wv_, __builtin_shufflevector(v2, v2, 4, 5), acc2[10]); \
    }

// single-pixel 25-tap conv
#define CONV_ACC_PK(acc2, lds, row0, col0, stride, W0, W1, W2, WL)                     \
    {                                                                                  \
        _Pragma("unroll")                                                              \
        for (int dy = 0; dy < KS; dy++) {                                              \
            _Pragma("unroll")                                                          \
            for (int dx = 0; dx < KS; dx++) {                                          \
                const f16 wt_ = WSEL(W0, W1, W2, WL, dy * KS + dx);                    \
                const half2v wv_ = {wt_, wt_};                                         \
                const f16* tp = (lds) + ((size_t)((row0) + dy) * (stride) + (col0) + dx) * CPAD; \
                half8 v0 = *(const half8*)(tp);                                        \
                half8 v1 = *(const half8*)(tp + 8);                                    \
                half8 v2 = *(const half8*)(tp + 16);                                   \
                TAP_PK(acc2, v0, v1, v2, wv_);                                         \
            }                                                                          \
        }                                                                              \
    }

// logits: l[c] = u[c] - acc2 (promote f16 acc to f32 here)
#define LOGITS_FROM_PK(l, acc2, U0, U1, U2)                                            \
    {                                                                                  \
        _Pragma("unroll")                                                              \
        for (int j = 0; j < 10; j++) {                                                 \
            l[2 * j]     = -(float)acc2[j][0];                                         \
            l[2 * j + 1] = -(float)acc2[j][1];                                         \
        }                                                                              \
        l[20] = -(float)acc2[10][0];                                                   \
        _Pragma("unroll")                                                              \
        for (int k = 0; k < 8; k++) l[k] += (float)U0[k];                              \
        _Pragma("unroll")                                                              \
        for (int k = 0; k < 8; k++) l[8 + k] += (float)U1[k];                          \
        _Pragma("unroll")                                                              \
        for (int k = 0; k < 5; k++) l[16 + k] += (float)U2[k];                         \
    }

// softmax over l[NCH] -> 3 packed half8
#define SOFTMAX_PACK(l, O0, O1, O2)                                                    \
    {                                                                                  \
        float m = l[0];                                                                \
        _Pragma("unroll")                                                              \
        for (int c = 1; c < NCH; c++) m = fmaxf(m, l[c]);                              \
        float s = 0.f;                                                                 \
        _Pragma("unroll")                                                              \
        for (int c = 0; c < NCH; c++) { l[c] = __expf(l[c] - m); s += l[c]; }          \
        float is = 1.0f / s;                                                           \
        _Pragma("unroll")                                                              \
        for (int k = 0; k < 8; k++) O0[k] = (f16)(l[k] * is);                          \
        _Pragma("unroll")                                                              \
        for (int k = 0; k < 8; k++) O1[k] = (f16)(l[8 + k] * is);                      \
        _Pragma("unroll")                                                              \
        for (int k = 0; k < 5; k++) O2[k] = (f16)(l[16 + k] * is);                     \
        O2[5] = (f16)0.f; O2[6] = (f16)0.f; O2[7] = (f16)0.f;                          \
    }

// ---------------- Kernel C: TWO fused CRF iterations, vertical px pair / thread ----------------
template <bool FINAL>
__global__ __launch_bounds__(NTHR, 4) void crf_pair_kernel(const f16* __restrict__ qin,
                                                           const f16* __restrict__ u16,
                                                           const f16* __restrict__ wcA,
                                                           const f16* __restrict__ wcB16,
                                                           void* __restrict__ qout) {
    __shared__ __align__(16) f16 buf[SPX][CPAD];   // 76800 B; staged q, then reused for q'

    const int tid = threadIdx.x;          // 0..511
    const int ixv = tid & (TW - 1);       // 0..31 (column)
    const int iyv = tid >> 5;             // 0..15 (pair row)

    // XCD band swizzle: 512 blocks; XCD (flat%8) owns 2 tile-rows per batch
    const int flat = blockIdx.x;
    const int band = flat & 7;
    const int within = flat >> 3;         // 0..63
    const int b = within >> 5;
    const int r = within & 31;
    const int x0 = (r & 15) * TW;
    const int y0 = (band * 2 + (r >> 4)) * TH;
    const int gx = x0 + ixv;
    const int gy0 = y0 + 2 * iyv;         // top pixel of vertical pair
    const size_t plane = (size_t)HH * WW;

    // ---- phase 1: async stage 40x40 q halo (4-px, for 2 iterations) ----
    const f16* qbase = qin + (size_t)b * plane * CPAD;
    f16* lbase = &buf[0][0];
    for (int idx = tid; idx < SCHUNK; idx += NTHR) {
        int px = idx / 3, h4 = idx - px * 3;
        int sly = px / SX, slx = px - sly * SX;
        int qy = refl(y0 - 4 + sly, HH);
        int qx = refl(x0 - 4 + slx, WW);
        const f16* g = qbase + ((size_t)(qy * WW + qx)) * CPAD + h4 * 8;
        __builtin_amdgcn_global_load_lds(
            (const __attribute__((address_space(1))) void*)g,
            (__attribute__((address_space(3))) void*)(lbase + (size_t)idx * 8),
            16, 0, 0);
    }

    // ---- fetch pair weights + unary (registers, used by BOTH iterations) ----
    const size_t pixoff0 = (size_t)b * plane + (size_t)gy0 * WW + gx;
    const size_t pixoff1 = pixoff0 + WW;
    const half8* wp0 = (const half8*)(wcA + pixoff0 * 24);
    half8 wa0 = wp0[0], wa1 = wp0[1], wa2 = wp0[2];
    f16 wl0 = wcB16[pixoff0];
    const half8* wp1 = (const half8*)(wcA + pixoff1 * 24);
    half8 wb0 = wp1[0], wb1 = wp1[1], wb2 = wp1[2];
    f16 wl1 = wcB16[pixoff1];
    const half8* up0 = (const half8*)(u16 + pixoff0 * CPAD);
    half8 uA0 = up0[0], uA1 = up0[1], uA2 = up0[2];
    const half8* up1 = (const half8*)(u16 + pixoff1 * CPAD);
    half8 uB0 = up1[0], uB1 = up1[1], uB2 = up1[2];

    // ---- ring pixel (threads 0..271): coords + weights + unary ----
    const bool has_ring = tid < RING;
    int rly = 0, rlx = 0;
    half8 wr0 = {}, wr1 = {}, wr2 = {}, ur0 = {}, ur1 = {}, ur2 = {};
    f16 wrl = (f16)0.f;
    if (has_ring) {
        int t = tid;
        if (t < 144) { int rr = t / 36; rly = (rr < 2) ? rr : 32 + rr; rlx = t % 36; }
        else         { int t2 = t - 144; rly = 2 + (t2 >> 2); int c = t2 & 3; rlx = (c < 2) ? c : (c + 32); }
        int rgy = y0 + rly - 2, rgx = x0 + rlx - 2;
        int cy = min(max(rgy, 0), HH - 1);
        int cx = min(max(rgx, 0), WW - 1);
        size_t rpo = (size_t)b * plane + (size_t)cy * WW + cx;
        const half8* wpr = (const half8*)(wcA + rpo * 24);
        wr0 = wpr[0]; wr1 = wpr[1]; wr2 = wpr[2];
        wrl = wcB16[rpo];
        const half8* upr = (const half8*)(u16 + rpo * CPAD);
        ur0 = upr[0]; ur1 = upr[1]; ur2 = upr[2];
    }

    __syncthreads();   // staged q + register loads resident

    // ---- phase 2: iteration k over extended 36x36 region ----
    half8 qr0, qr1, qr2;   // ring q'
    if (has_ring) {
        half2v acc2[11];
#pragma unroll
        for (int j = 0; j < 11; j++) acc2[j] = (half2v){(f16)0.f, (f16)0.f};
        CONV_ACC_PK(acc2, lbase, rly, rlx, SX, wr0, wr1, wr2, wrl);
        float l[NCH];
        LOGITS_FROM_PK(l, acc2, ur0, ur1, ur2);
        SOFTMAX_PACK(l, qr0, qr1, qr2);
    }

    // inner vertical pair, shared 6-row x 5-col window from staged tile
    half8 qiA0, qiA1, qiA2, qiB0, qiB1, qiB2;
    {
        half2v accA[11], accB[11];
#pragma unroll
        for (int j = 0; j < 11; j++) {
            accA[j] = (half2v){(f16)0.f, (f16)0.f};
            accB[j] = (half2v){(f16)0.f, (f16)0.f};
        }
        const int row0 = 2 * iyv + 2;     // staged coords of window top row
        const int col0 = ixv + 2;
#pragma unroll
        for (int dy = 0; dy < 6; dy++) {
#pragma unroll
            for (int dx = 0; dx < KS; dx++) {
                const f16* tp = lbase + ((size_t)(row0 + dy) * SX + col0 + dx) * CPAD;
                half8 v0 = *(const half8*)(tp);
                half8 v1 = *(const half8*)(tp + 8);
                half8 v2 = *(const half8*)(tp + 16);
                if (dy < 5) {
                    const f16 wt_ = WSEL(wa0, wa1, wa2, wl0, dy * KS + dx);
                    const half2v wv_ = {wt_, wt_};
                    TAP_PK(accA, v0, v1, v2, wv_);
                }
                if (dy >= 1) {
                    const f16 wt_ = WSEL(wb0, wb1, wb2, wl1, (dy - 1) * KS + dx);
                    const half2v wv_ = {wt_, wt_};
                    TAP_PK(accB, v0, v1, v2, wv_);
                }
            }
        }
        float l[NCH];
        LOGITS_FROM_PK(l, accA, uA0, uA1, uA2);
        SOFTMAX_PACK(l, qiA0, qiA1, qiA2);
        LOGITS_FROM_PK(l, accB, uB0, uB1, uB2);
        SOFTMAX_PACK(l, qiB0, qiB1, qiB2);
    }

    __syncthreads();   // all reads of staged q complete

    // ---- phase 3: park q' in LDS (reuse buf; layout [EPX][24], stride EX) ----
    {
        half8* d0 = (half8*)(lbase + ((size_t)(2 * iyv + 2) * EX + (ixv + 2)) * CPAD);
        d0[0] = qiA0; d0[1] = qiA1; d0[2] = qiA2;
        half8* d1 = (half8*)(lbase + ((size_t)(2 * iyv + 3) * EX + (ixv + 2)) * CPAD);
        d1[0] = qiB0; d1[1] = qiB1; d1[2] = qiB2;
        if (has_ring) {
            half8* dr = (half8*)(lbase + ((size_t)rly * EX + rlx) * CPAD);
            dr[0] = qr0; dr[1] = qr1; dr[2] = qr2;
        }
    }

    __syncthreads();

    // ---- phase 4: iteration k+1 at the inner pair (w,u from registers) ----
    {
        int ryy[6], rxx[KS];
#pragma unroll
        for (int d = 0; d < 6; d++) ryy[d] = refl(gy0 + d - 2, HH) - (y0 - 2);
#pragma unroll
        for (int d = 0; d < KS; d++) rxx[d] = refl(gx + d - 2, WW) - (x0 - 2);

        half2v accA[11], accB[11];
#pragma unroll
        for (int j = 0; j < 11; j++) {
            accA[j] = (half2v){(f16)0.f, (f16)0.f};
            accB[j] = (half2v){(f16)0.f, (f16)0.f};
        }
#pragma unroll
        for (int dy = 0; dy < 6; dy++) {
#pragma unroll
            for (int dx = 0; dx < KS; dx++) {
                const f16* tp = lbase + ((size_t)ryy[dy] * EX + rxx[dx]) * CPAD;
                half8 v0 = *(const half8*)(tp);
                half8 v1 = *(const half8*)(tp + 8);
                half8 v2 = *(const half8*)(tp + 16);
                if (dy < 5) {
                    const f16 wt_ = WSEL(wa0, wa1, wa2, wl0, dy * KS + dx);
                    const half2v wv_ = {wt_, wt_};
                    TAP_PK(accA, v0, v1, v2, wv_);
                }
                if (dy >= 1) {
                    const f16 wt_ = WSEL(wb0, wb1, wb2, wl1, (dy - 1) * KS + dx);
                    const half2v wv_ = {wt_, wt_};
                    TAP_PK(accB, v0, v1, v2, wv_);
                }
            }
        }
        float l0[NCH], l1[NCH];
        LOGITS_FROM_PK(l0, accA, uA0, uA1, uA2);
        LOGITS_FROM_PK(l1, accB, uB0, uB1, uB2);

        if (FINAL) {
            float m0 = l0[0], m1 = l1[0];
#pragma unroll
            for (int c = 1; c < NCH; c++) { m0 = fmaxf(m0, l0[c]); m1 = fmaxf(m1, l1[c]); }
            float s0 = 0.f, s1 = 0.f;
#pragma unroll
            for (int c = 0; c < NCH; c++) {
                l0[c] = __expf(l0[c] - m0); s0 += l0[c];
                l1[c] = __expf(l1[c] - m1); s1 += l1[c];
            }
            float is0 = 1.0f / s0, is1 = 1.0f / s1;
            float* qo = (float*)qout + (size_t)b * NCH * plane + (size_t)gy0 * WW + gx;
#pragma unroll
            for (int c = 0; c < NCH; c++) {
                qo[c * plane] = l0[c] * is0;
                qo[c * plane + WW] = l1[c] * is1;
            }
        } else {
            half8 o0, o1, o2;
            SOFTMAX_PACK(l0, o0, o1, o2);
            half8* q0 = (half8*)((f16*)qout + pixoff0 * CPAD);
            q0[0] = o0; q0[1] = o1; q0[2] = o2;
            SOFTMAX_PACK(l1, o0, o1, o2);
            half8* q1 = (half8*)((f16*)qout + pixoff1 * CPAD);
            q1[0] = o0; q1[1] = o1; q1[2] = o2;
        }
    }
}

extern "C" void kernel_launch(void* const* d_in, const int* in_sizes, int n_in,
                              void* d_out, int out_size, void* d_ws, size_t ws_size,
                              hipStream_t stream) {
    const float* unary = (const float*)d_in[0];   // B,21,512,512
    const float* image = (const float*)d_in[1];   // B,3,512,512
    const float* edges = (const float*)d_in[2];   // B,512,512
    float* out = (float*)d_out;                   // B,21,512,512 fp32

    const size_t plane = (size_t)HH * WW;
    char* ws = (char*)d_ws;
    f16* wcA = (f16*)ws;                                         // B*plane*24 f16 = 25.2 MB
    char* p1 = ws + sizeof(f16) * BATCH * plane * 24;
    f16* wcB16 = (f16*)p1;                                       // B*plane f16    =  1.0 MB
    char* p2 = p1 + sizeof(f16) * BATCH * plane;
    f16* u16 = (f16*)p2;                                         // 25.2 MB
    char* p3 = p2 + sizeof(f16) * BATCH * plane * CPAD;
    f16* qA = (f16*)p3;                                          // 25.2 MB
    f16* qB = qA + (size_t)BATCH * plane * CPAD;                 // 25.2 MB (total ~102 MB)

    const int npix = BATCH * HH * WW;
    dim3 gridW(WW / TXW, HH / TYW, BATCH);
    dim3 blockW(TXW, TYW, 1);
    weights_kernel<<<gridW, blockW, 0, stream>>>(image, edges, wcA, wcB16);
    init_kernel<<<(npix + 255) / 256, 256, 0, stream>>>(unary, qA, u16);

    const int nblk = (WW / TW) * (HH / TH) * BATCH;   // 512
    f16* qa = qA;
    f16* qb = qB;
    const int npairs = NUM_ITERS / 2;                 // 5
    for (int it = 0; it < npairs - 1; it++) {
        crf_pair_kernel<false><<<nblk, NTHR, 0, stream>>>(qa, u16, wcA, wcB16, (void*)qb);
        f16* t = qa; qa = qb; qb = t;
    }
    crf_pair_kernel<true><<<nblk, NTHR, 0, stream>>>(qa, u16, wcA, wcB16, (void*)out);
}

// Round 11
// 390.676 us; speedup vs baseline: 2.1289x; 2.1289x over previous
//
#include <hip/hip_runtime.h>
#include <math.h>

#define BATCH 2
#define NCH 21
#define CPAD 24            // channels padded to 24 (48 B fp16 per pixel)
#define HH 512
#define WW 512
#define KS 5
#define RAD 2
#define NTAPS 25
#define NUM_ITERS 10

// weights-kernel tile geometry
#define TXW 32
#define TYW 8
#define HXW (TXW + 2*RAD)   // 36
#define HYW (TYW + 2*RAD)   // 12
#define HPXW (HXW * HYW)    // 432

// fused-pair kernel geometry: 32x16 inner tile, 256 threads, vertical px pair per thread
#define TW 32
#define TH 16
#define NTHR 256
#define SX 40               // staged tile (4-px halo for 2 iters)
#define SY 24
#define SPX (SX * SY)       // 960
#define SCHUNK (SPX * 3)    // 2880 16-byte DMA chunks
#define EX 36               // extended (iter-1 output) region
#define EY 20
#define EPX (EX * EY)       // 720
#define RING (EPX - TW*TH)  // 208 ring pixels

typedef _Float16 f16;
typedef _Float16 half8 __attribute__((ext_vector_type(8)));
typedef _Float16 half2v __attribute__((ext_vector_type(2)));

__device__ __forceinline__ int refl(int i, int n) {
    if (i < 0) i = -i;
    if (i >= n) i = 2*n - 2 - i;
    return i;
}

// weight-element selector (t is a compile-time constant after unrolling)
#define WSEL(h0, h1, h2, hl, t) \
    ((t) < 8 ? (h0)[(t)] : (t) < 16 ? (h1)[(t) - 8] : (t) < 24 ? (h2)[(t) - 16] : (hl))

// ---------------- Kernel A: combined normalized weights ----------------
// layout: wcA[px][24 halfs] (taps 0..23 interleaved) + wcB16[px] (tap 24)
__global__ __launch_bounds__(256) void weights_kernel(const float* __restrict__ image,
                                                      const float* __restrict__ edges,
                                                      f16* __restrict__ wcA,
                                                      f16* __restrict__ wcB16) {
    __shared__ float sr_[HYW][HXW];
    __shared__ float sg_[HYW][HXW];
    __shared__ float sb_[HYW][HXW];
    __shared__ float se_[HYW][HXW];

    const int tx = threadIdx.x;
    const int ty = threadIdx.y;
    const int tid = ty * TXW + tx;
    const int x0 = blockIdx.x * TXW;
    const int y0 = blockIdx.y * TYW;
    const int b = blockIdx.z;
    const int x = x0 + tx;
    const int y = y0 + ty;
    const size_t plane = (size_t)HH * WW;
    const float* img = image + (size_t)b * 3 * plane;
    const float* edg = edges + (size_t)b * plane;

    for (int i = tid; i < HPXW; i += TXW * TYW) {
        int ly = i / HXW, lx = i - ly * HXW;
        int gy = refl(y0 + ly - RAD, HH);
        int gx = refl(x0 + lx - RAD, WW);
        int g = gy * WW + gx;
        sr_[ly][lx] = img[g];
        sg_[ly][lx] = img[plane + g];
        sb_[ly][lx] = img[2 * plane + g];
        se_[ly][lx] = edg[g];
    }
    __syncthreads();

    float gs[3];
    gs[0] = 1.0f; gs[1] = __expf(-1.0f / 50.0f); gs[2] = __expf(-4.0f / 50.0f);
    float gb[3];
    gb[0] = 1.0f; gb[1] = __expf(-2.0f); gb[2] = __expf(-8.0f);
    float gbs = gb[0] + 2.0f * (gb[1] + gb[2]);
    gb[0] /= gbs; gb[1] /= gbs; gb[2] /= gbs;

    const float r0 = sr_[ty + RAD][tx + RAD];
    const float g0 = sg_[ty + RAD][tx + RAD];
    const float b0 = sb_[ty + RAD][tx + RAD];
    const float e0 = se_[ty + RAD][tx + RAD];

    float wr[NTAPS], we[NTAPS];
    float sr = 0.f, se = 0.f;
#pragma unroll
    for (int dy = 0; dy < KS; dy++) {
#pragma unroll
        for (int dx = 0; dx < KS; dx++) {
            float sp = gs[abs(dy - RAD)] * gs[abs(dx - RAD)];
            float d = fabsf(sr_[ty + dy][tx + dx] - r0)
                    + fabsf(sg_[ty + dy][tx + dx] - g0)
                    + fabsf(sb_[ty + dy][tx + dx] - b0);
            float w1 = sp * __expf(-2.0f * d * d);
            float de = fabsf(se_[ty + dy][tx + dx] - e0);
            float w2 = sp * __expf(-2.0f * de * de);
            wr[dy * KS + dx] = w1;
            we[dy * KS + dx] = w2;
            sr += w1;
            se += w2;
        }
    }
    float isr = 1.0f / sr, ise = 1.0f / se;
    float wt[NTAPS];
#pragma unroll
    for (int t = 0; t < NTAPS; t++) {
        int dy = t / KS, dx = t % KS;
        float g2 = gb[abs(dy - RAD)] * gb[abs(dx - RAD)];
        wt[t] = g2 + wr[t] * isr + we[t] * ise;
    }
    const size_t pixoff = (size_t)b * plane + (size_t)y * WW + x;
    half8* wo = (half8*)(wcA + pixoff * 24);
#pragma unroll
    for (int g = 0; g < 3; g++) {
        half8 v;
#pragma unroll
        for (int k = 0; k < 8; k++) v[k] = (f16)wt[g * 8 + k];
        wo[g] = v;
    }
    wcB16[pixoff] = (f16)wt[24];
}

// ---------------- Kernel B: initial softmax -> interleaved fp16 q + fp16 unary ----------------
__global__ void init_kernel(const float* __restrict__ unary,
                            f16* __restrict__ q,
                            f16* __restrict__ u16) {
    int idx = blockIdx.x * blockDim.x + threadIdx.x;
    if (idx >= BATCH * HH * WW) return;
    int p = idx % (HH * WW);
    int b = idx / (HH * WW);
    const size_t plane = (size_t)HH * WW;
    const float* u = unary + (size_t)b * NCH * plane + p;
    float l[CPAD];
    float m = -1e30f;
#pragma unroll
    for (int c = 0; c < NCH; c++) { l[c] = u[c * plane]; m = fmaxf(m, l[c]); }
    l[21] = 0.f; l[22] = 0.f; l[23] = 0.f;

    half8* uo = (half8*)(u16 + ((size_t)b * plane + p) * CPAD);
#pragma unroll
    for (int g = 0; g < 3; g++) {
        half8 v;
#pragma unroll
        for (int k = 0; k < 8; k++) v[k] = (f16)l[g * 8 + k];
        uo[g] = v;
    }

    float s = 0.f;
    float e[CPAD];
#pragma unroll
    for (int c = 0; c < NCH; c++) { e[c] = __expf(l[c] - m); s += e[c]; }
    float is = 1.0f / s;
    e[21] = 0.f; e[22] = 0.f; e[23] = 0.f;
    half8* qo = (half8*)(q + ((size_t)b * plane + p) * CPAD);
#pragma unroll
    for (int g = 0; g < 3; g++) {
        half8 v;
#pragma unroll
        for (int k = 0; k < 8; k++) v[k] = (f16)(e[g * 8 + k] * is);
        qo[g] = v;
    }
}

// packed-f16 FMA of one tap into an 11-element half2 accumulator
#define TAP_PK(acc2, v0, v1, v2, wv_)                                                           \
    {                                                                                           \
        acc2[0]  = __builtin_elementwise_fma(wv_, __builtin_shufflevector(v0, v0, 0, 1), acc2[0]);  \
        acc2[1]  = __builtin_elementwise_fma(wv_, __builtin_shufflevector(v0, v0, 2, 3), acc2[1]);  \
        acc2[2]  = __builtin_elementwise_fma(wv_, __builtin_shufflevector(v0, v0, 4, 5), acc2[2]);  \
        acc2[3]  = __builtin_elementwise_fma(wv_, __builtin_shufflevector(v0, v0, 6, 7), acc2[3]);  \
        acc2[4]  = __builtin_elementwise_fma(wv_, __builtin_shufflevector(v1, v1, 0, 1), acc2[4]);  \
        acc2[5]  = __builtin_elementwise_fma(wv_, __builtin_shufflevector(v1, v1, 2, 3), acc2[5]);  \
        acc2[6]  = __builtin_elementwise_fma(wv_, __builtin_shufflevector(v1, v1, 4, 5), acc2[6]);  \
        acc2[7]  = __builtin_elementwise_fma(wv_, __builtin_shufflevector(v1, v1, 6, 7), acc2[7]);  \
        acc2[8]  = __builtin_elementwise_fma(wv_, __builtin_shufflevector(v2, v2, 0, 1), acc2[8]);  \
        acc2[9]  = __builtin_elementwise_fma(wv_, __builtin_shufflevector(v2, v2, 2, 3), acc2[9]);  \
        acc2[10] = __builtin_elementwise_fma(wv_, __builtin_shufflevector(v2, v2, 4, 5), acc2[10]); \
    }

// single-pixel 25-tap conv
#define CONV_ACC_PK(acc2, lds, row0, col0, stride, W0, W1, W2, WL)                     \
    {                                                                                  \
        _Pragma("unroll")                                                              \
        for (int dy = 0; dy < KS; dy++) {                                              \
            _Pragma("unroll")                                                          \
            for (int dx = 0; dx < KS; dx++) {                                          \
                const f16 wt_ = WSEL(W0, W1, W2, WL, dy * KS + dx);                    \
                const half2v wv_ = {wt_, wt_};                                         \
                const f16* tp = (lds) + ((size_t)((row0) + dy) * (stride) + (col0) + dx) * CPAD; \
                half8 v0 = *(const half8*)(tp);                                        \
                half8 v1 = *(const half8*)(tp + 8);                                    \
                half8 v2 = *(const half8*)(tp + 16);                                   \
                TAP_PK(acc2, v0, v1, v2, wv_);                                         \
            }                                                                          \
        }                                                                              \
    }

// vertical-pair conv: 6x5 shared window, rows d=0..5 at (rowAddr[d]), accA taps d<5, accB taps d>=1
#define CONV_PAIR_PK(accA, accB, lds, rowaddr, coladdr, stride, WA0, WA1, WA2, WLA, WB0, WB1, WB2, WLB) \
    {                                                                                  \
        _Pragma("unroll")                                                              \
        for (int dy = 0; dy < 6; dy++) {                                               \
            _Pragma("unroll")                                                          \
            for (int dx = 0; dx < KS; dx++) {                                          \
                const f16* tp = (lds) + ((size_t)(rowaddr[dy]) * (stride) + (coladdr[dx])) * CPAD; \
                half8 v0 = *(const half8*)(tp);                                        \
                half8 v1 = *(const half8*)(tp + 8);                                    \
                half8 v2 = *(const half8*)(tp + 16);                                   \
                if (dy < 5) {                                                          \
                    const f16 wt_ = WSEL(WA0, WA1, WA2, WLA, dy * KS + dx);            \
                    const half2v wv_ = {wt_, wt_};                                     \
                    TAP_PK(accA, v0, v1, v2, wv_);                                     \
                }                                                                      \
                if (dy >= 1) {                                                         \
                    const f16 wt_ = WSEL(WB0, WB1, WB2, WLB, (dy - 1) * KS + dx);      \
                    const half2v wv_ = {wt_, wt_};                                     \
                    TAP_PK(accB, v0, v1, v2, wv_);                                     \
                }                                                                      \
            }                                                                          \
        }                                                                              \
    }

// logits: l[c] = u[c] - acc2 (promote f16 acc to f32 here)
#define LOGITS_FROM_PK(l, acc2, U0, U1, U2)                                            \
    {                                                                                  \
        _Pragma("unroll")                                                              \
        for (int j = 0; j < 10; j++) {                                                 \
            l[2 * j]     = -(float)acc2[j][0];                                         \
            l[2 * j + 1] = -(float)acc2[j][1];                                         \
        }                                                                              \
        l[20] = -(float)acc2[10][0];                                                   \
        _Pragma("unroll")                                                              \
        for (int k = 0; k < 8; k++) l[k] += (float)U0[k];                              \
        _Pragma("unroll")                                                              \
        for (int k = 0; k < 8; k++) l[8 + k] += (float)U1[k];                          \
        _Pragma("unroll")                                                              \
        for (int k = 0; k < 5; k++) l[16 + k] += (float)U2[k];                         \
    }

// softmax over l[NCH] -> 3 packed half8
#define SOFTMAX_PACK(l, O0, O1, O2)                                                    \
    {                                                                                  \
        float m = l[0];                                                                \
        _Pragma("unroll")                                                              \
        for (int c = 1; c < NCH; c++) m = fmaxf(m, l[c]);                              \
        float s = 0.f;                                                                 \
        _Pragma("unroll")                                                              \
        for (int c = 0; c < NCH; c++) { l[c] = __expf(l[c] - m); s += l[c]; }          \
        float is = 1.0f / s;                                                           \
        _Pragma("unroll")                                                              \
        for (int k = 0; k < 8; k++) O0[k] = (f16)(l[k] * is);                          \
        _Pragma("unroll")                                                              \
        for (int k = 0; k < 8; k++) O1[k] = (f16)(l[8 + k] * is);                      \
        _Pragma("unroll")                                                              \
        for (int k = 0; k < 5; k++) O2[k] = (f16)(l[16 + k] * is);                     \
        O2[5] = (f16)0.f; O2[6] = (f16)0.f; O2[7] = (f16)0.f;                          \
    }

// ---------------- Kernel C: TWO fused CRF iterations, vertical px pair / thread ----------------
template <bool FINAL>
__global__ __launch_bounds__(NTHR, 4) void crf_pair_kernel(const f16* __restrict__ qin,
                                                           const f16* __restrict__ u16,
                                                           const f16* __restrict__ wcA,
                                                           const f16* __restrict__ wcB16,
                                                           void* __restrict__ qout) {
    __shared__ __align__(16) f16 buf[SPX][CPAD];   // 46080 B; staged q, then reused for q'

    const int tid = threadIdx.x;          // 0..255
    const int ixv = tid & (TW - 1);       // 0..31 (column)
    const int iyv = tid >> 5;             // 0..7  (pair row)

    // XCD band swizzle: 1024 blocks; XCD (flat%8) owns 4 tile-rows per batch
    const int flat = blockIdx.x;
    const int band = flat & 7;
    const int within = flat >> 3;         // 0..127
    const int b = within >> 6;
    const int r = within & 63;
    const int x0 = (r & 15) * TW;
    const int y0 = (band * 4 + (r >> 4)) * TH;
    const int gx = x0 + ixv;
    const int gy0 = y0 + 2 * iyv;         // top pixel of vertical pair
    const size_t plane = (size_t)HH * WW;

    // ---- phase 1: async stage 24x40 q halo (4-px, for 2 iterations) ----
    const f16* qbase = qin + (size_t)b * plane * CPAD;
    f16* lbase = &buf[0][0];
    for (int idx = tid; idx < SCHUNK; idx += NTHR) {
        int px = idx / 3, h4 = idx - px * 3;
        int sly = px / SX, slx = px - sly * SX;
        int qy = refl(y0 - 4 + sly, HH);
        int qx = refl(x0 - 4 + slx, WW);
        const f16* g = qbase + ((size_t)(qy * WW + qx)) * CPAD + h4 * 8;
        __builtin_amdgcn_global_load_lds(
            (const __attribute__((address_space(1))) void*)g,
            (__attribute__((address_space(3))) void*)(lbase + (size_t)idx * 8),
            16, 0, 0);
    }

    // ---- fetch pair weights (registers, used by BOTH iterations); unary is re-read per phase ----
    const size_t pixoff0 = (size_t)b * plane + (size_t)gy0 * WW + gx;
    const size_t pixoff1 = pixoff0 + WW;
    const half8* wp0 = (const half8*)(wcA + pixoff0 * 24);
    half8 wa0 = wp0[0], wa1 = wp0[1], wa2 = wp0[2];
    f16 wl0 = wcB16[pixoff0];
    const half8* wp1 = (const half8*)(wcA + pixoff1 * 24);
    half8 wb0 = wp1[0], wb1 = wp1[1], wb2 = wp1[2];
    f16 wl1 = wcB16[pixoff1];

    // ---- ring pixel (threads 0..207): coords + weights + unary (phase-2 lifetime only) ----
    const bool has_ring = tid < RING;
    int rly = 0, rlx = 0;
    half8 wr0 = {}, wr1 = {}, wr2 = {}, ur0 = {}, ur1 = {}, ur2 = {};
    f16 wrl = (f16)0.f;
    if (has_ring) {
        int t = tid;
        if (t < 72)       { rly = t / 36;       rlx = t % 36; }
        else if (t < 144) { t -= 72;  rly = 18 + t / 36; rlx = t % 36; }
        else              { t -= 144; rly = 2 + (t >> 2); int c = t & 3; rlx = (c < 2) ? c : (c + 32); }
        int rgy = y0 + rly - 2, rgx = x0 + rlx - 2;
        int cy = min(max(rgy, 0), HH - 1);
        int cx = min(max(rgx, 0), WW - 1);
        size_t rpo = (size_t)b * plane + (size_t)cy * WW + cx;
        const half8* wpr = (const half8*)(wcA + rpo * 24);
        wr0 = wpr[0]; wr1 = wpr[1]; wr2 = wpr[2];
        wrl = wcB16[rpo];
        const half8* upr = (const half8*)(u16 + rpo * CPAD);
        ur0 = upr[0]; ur1 = upr[1]; ur2 = upr[2];
    }

    __syncthreads();   // staged q + register loads resident

    // ---- phase 2: iteration k over extended 36x20 region ----
    half8 qr0, qr1, qr2;   // ring q' (ring w/u regs die after this)
    if (has_ring) {
        half2v acc2[11];
#pragma unroll
        for (int j = 0; j < 11; j++) acc2[j] = (half2v){(f16)0.f, (f16)0.f};
        CONV_ACC_PK(acc2, lbase, rly, rlx, SX, wr0, wr1, wr2, wrl);
        float l[NCH];
        LOGITS_FROM_PK(l, acc2, ur0, ur1, ur2);
        SOFTMAX_PACK(l, qr0, qr1, qr2);
    }

    // inner vertical pair, shared 6-row x 5-col window from staged tile
    half8 qiA0, qiA1, qiA2, qiB0, qiB1, qiB2;
    {
        half2v accA[11], accB[11];
#pragma unroll
        for (int j = 0; j < 11; j++) {
            accA[j] = (half2v){(f16)0.f, (f16)0.f};
            accB[j] = (half2v){(f16)0.f, (f16)0.f};
        }
        int rowaddr[6], coladdr[KS];
#pragma unroll
        for (int d = 0; d < 6; d++) rowaddr[d] = 2 * iyv + 2 + d;
#pragma unroll
        for (int d = 0; d < KS; d++) coladdr[d] = ixv + 2 + d;
        CONV_PAIR_PK(accA, accB, lbase, rowaddr, coladdr, SX,
                     wa0, wa1, wa2, wl0, wb0, wb1, wb2, wl1);
        // re-read pair unary (L2-warm), then logits+softmax
        const half8* up0 = (const half8*)(u16 + pixoff0 * CPAD);
        half8 uA0 = up0[0], uA1 = up0[1], uA2 = up0[2];
        const half8* up1 = (const half8*)(u16 + pixoff1 * CPAD);
        half8 uB0 = up1[0], uB1 = up1[1], uB2 = up1[2];
        float l[NCH];
        LOGITS_FROM_PK(l, accA, uA0, uA1, uA2);
        SOFTMAX_PACK(l, qiA0, qiA1, qiA2);
        LOGITS_FROM_PK(l, accB, uB0, uB1, uB2);
        SOFTMAX_PACK(l, qiB0, qiB1, qiB2);
    }

    __syncthreads();   // all reads of staged q complete

    // ---- phase 3: park q' in LDS (reuse buf; layout [EPX][24], stride EX) ----
    {
        half8* d0 = (half8*)(lbase + ((size_t)(2 * iyv + 2) * EX + (ixv + 2)) * CPAD);
        d0[0] = qiA0; d0[1] = qiA1; d0[2] = qiA2;
        half8* d1 = (half8*)(lbase + ((size_t)(2 * iyv + 3) * EX + (ixv + 2)) * CPAD);
        d1[0] = qiB0; d1[1] = qiB1; d1[2] = qiB2;
        if (has_ring) {
            half8* dr = (half8*)(lbase + ((size_t)rly * EX + rlx) * CPAD);
            dr[0] = qr0; dr[1] = qr1; dr[2] = qr2;
        }
    }

    __syncthreads();

    // ---- phase 4: iteration k+1 at the inner pair (w from registers, u re-read) ----
    {
        int ryy[6], rxx[KS];
#pragma unroll
        for (int d = 0; d < 6; d++) ryy[d] = refl(gy0 + d - 2, HH) - (y0 - 2);
#pragma unroll
        for (int d = 0; d < KS; d++) rxx[d] = refl(gx + d - 2, WW) - (x0 - 2);

        half2v accA[11], accB[11];
#pragma unroll
        for (int j = 0; j < 11; j++) {
            accA[j] = (half2v){(f16)0.f, (f16)0.f};
            accB[j] = (half2v){(f16)0.f, (f16)0.f};
        }
        CONV_PAIR_PK(accA, accB, lbase, ryy, rxx, EX,
                     wa0, wa1, wa2, wl0, wb0, wb1, wb2, wl1);

        const half8* up0 = (const half8*)(u16 + pixoff0 * CPAD);
        half8 uA0 = up0[0], uA1 = up0[1], uA2 = up0[2];
        const half8* up1 = (const half8*)(u16 + pixoff1 * CPAD);
        half8 uB0 = up1[0], uB1 = up1[1], uB2 = up1[2];

        float l0[NCH], l1[NCH];
        LOGITS_FROM_PK(l0, accA, uA0, uA1, uA2);
        LOGITS_FROM_PK(l1, accB, uB0, uB1, uB2);

        if (FINAL) {
            float m0 = l0[0], m1 = l1[0];
#pragma unroll
            for (int c = 1; c < NCH; c++) { m0 = fmaxf(m0, l0[c]); m1 = fmaxf(m1, l1[c]); }
            float s0 = 0.f, s1 = 0.f;
#pragma unroll
            for (int c = 0; c < NCH; c++) {
                l0[c] = __expf(l0[c] - m0); s0 += l0[c];
                l1[c] = __expf(l1[c] - m1); s1 += l1[c];
            }
            float is0 = 1.0f / s0, is1 = 1.0f / s1;
            float* qo = (float*)qout + (size_t)b * NCH * plane + (size_t)gy0 * WW + gx;
#pragma unroll
            for (int c = 0; c < NCH; c++) {
                qo[c * plane] = l0[c] * is0;
                qo[c * plane + WW] = l1[c] * is1;
            }
        } else {
            half8 o0, o1, o2;
            SOFTMAX_PACK(l0, o0, o1, o2);
            half8* q0 = (half8*)((f16*)qout + pixoff0 * CPAD);
            q0[0] = o0; q0[1] = o1; q0[2] = o2;
            SOFTMAX_PACK(l1, o0, o1, o2);
            half8* q1 = (half8*)((f16*)qout + pixoff1 * CPAD);
            q1[0] = o0; q1[1] = o1; q1[2] = o2;
        }
    }
}

extern "C" void kernel_launch(void* const* d_in, const int* in_sizes, int n_in,
                              void* d_out, int out_size, void* d_ws, size_t ws_size,
                              hipStream_t stream) {
    const float* unary = (const float*)d_in[0];   // B,21,512,512
    const float* image = (const float*)d_in[1];   // B,3,512,512
    const float* edges = (const float*)d_in[2];   // B,512,512
    float* out = (float*)d_out;                   // B,21,512,512 fp32

    const size_t plane = (size_t)HH * WW;
    char* ws = (char*)d_ws;
    f16* wcA = (f16*)ws;                                         // B*plane*24 f16 = 25.2 MB
    char* p1 = ws + sizeof(f16) * BATCH * plane * 24;
    f16* wcB16 = (f16*)p1;                                       // B*plane f16    =  1.0 MB
    char* p2 = p1 + sizeof(f16) * BATCH * plane;
    f16* u16 = (f16*)p2;                                         // 25.2 MB
    char* p3 = p2 + sizeof(f16) * BATCH * plane * CPAD;
    f16* qA = (f16*)p3;                                          // 25.2 MB
    f16* qB = qA + (size_t)BATCH * plane * CPAD;                 // 25.2 MB (total ~102 MB)

    const int npix = BATCH * HH * WW;
    dim3 gridW(WW / TXW, HH / TYW, BATCH);
    dim3 blockW(TXW, TYW, 1);
    weights_kernel<<<gridW, blockW, 0, stream>>>(image, edges, wcA, wcB16);
    init_kernel<<<(npix + 255) / 256, 256, 0, stream>>>(unary, qA, u16);

    const int nblk = (WW / TW) * (HH / TH) * BATCH;   // 1024
    f16* qa = qA;
    f16* qb = qB;
    const int npairs = NUM_ITERS / 2;                 // 5
    for (int it = 0; it < npairs - 1; it++) {
        crf_pair_kernel<false><<<nblk, NTHR, 0, stream>>>(qa, u16, wcA, wcB16, (void*)qb);
        f16* t = qa; qa = qb; qb = t;
    }
    crf_pair_kernel<true><<<nblk, NTHR, 0, stream>>>(qa, u16, wcA, wcB16, (void*)out);
}